// Round 6
// baseline (452.894 us; speedup 1.0000x reference)
//
#include <hip/hip_runtime.h>
#include <math.h>

// B0=2048 tokens, C=512, P=32 past, R=8 selected, H=8 heads, DH=64, HID=256
// fp32 exact path for top-k scores (Wqk trick); bf16 MFMA (BK=64 m97
// structure, swapped-operand epilogue for vectorized stores) downstream.

typedef __attribute__((ext_vector_type(8))) __bf16 bf16x8;
typedef __attribute__((ext_vector_type(4))) float f32x4;
typedef unsigned short u16;
typedef unsigned int u32;

static __device__ __forceinline__ float4 ld4(const float* p) { return *(const float4*)p; }
static __device__ __forceinline__ float gelu_exact(float x) {
  return 0.5f * x * (1.0f + erff(x * 0.70710678118654752f));
}
static __device__ __forceinline__ u16 f2bf(float f) {  // RNE
  u32 u = __float_as_uint(f);
  u = (u + 0x7fffu + ((u >> 16) & 1u)) >> 16;
  return (u16)u;
}
static __device__ __forceinline__ float bf2f(u16 h) {
  return __uint_as_float(((u32)h) << 16);
}
static __device__ __forceinline__ u32 pk2(float a, float b) {
  return (u32)f2bf(a) | ((u32)f2bf(b) << 16);
}
static __device__ __forceinline__ void ld8bf(const u16* p, float* o) {
  int4 v = *(const int4*)p;
  o[0] = bf2f((u16)((u32)v.x & 0xffffu)); o[1] = bf2f((u16)(((u32)v.x) >> 16));
  o[2] = bf2f((u16)((u32)v.y & 0xffffu)); o[3] = bf2f((u16)(((u32)v.y) >> 16));
  o[4] = bf2f((u16)((u32)v.z & 0xffffu)); o[5] = bf2f((u16)(((u32)v.z) >> 16));
  o[6] = bf2f((u16)((u32)v.w & 0xffffu)); o[7] = bf2f((u16)(((u32)v.w) >> 16));
}
static __device__ __forceinline__ void gld16(const void* g, void* l) {
  __builtin_amdgcn_global_load_lds((const __attribute__((address_space(1))) void*)g,
                                   (__attribute__((address_space(3))) void*)l, 16, 0, 0);
}
// stage NI*32 rows x 64 k (u16) into lds; sp is the per-lane source position:
//   sp = base + (size_t)((w<<3)+(lane>>3))*ldk + ((lane&7)<<3)
template <int NI>
static __device__ __forceinline__ void stageT(u16* __restrict__ lds,
                                              const u16* __restrict__ sp,
                                              int ldk, int w) {
#pragma unroll
  for (int i = 0; i < NI; ++i)
    gld16(sp + (size_t)(i << 5) * ldk, lds + (w << 9) + (i << 11));
}

// ---------------------------------------------------------------------------
// prep_all: blocks 0-1663 bf16 weight transposes; blocks 1664-1919 fp32 Wqk.
// ---------------------------------------------------------------------------
__global__ __launch_bounds__(256) void prep_all(
    const float* __restrict__ Wq, const float* __restrict__ Wk,
    const float* __restrict__ Wv, const float* __restrict__ W1,
    const float* __restrict__ W2, const float* __restrict__ Wo,
    u16* __restrict__ Wqkvt, u16* __restrict__ W1t,
    u16* __restrict__ W2t, u16* __restrict__ Wot,
    float* __restrict__ Wqk) {
  const int b = blockIdx.x;
  if (b < 1664) {
    __shared__ float t[32][33];
    const float* S; u16* D; int lds_, Kd, nx, t0;
    if (b < 256)       { S = Wq; D = Wqkvt;              lds_ = 512;  Kd = 512;  nx = 16; t0 = 0; }
    else if (b < 512)  { S = Wk; D = Wqkvt + 512 * 512;  lds_ = 512;  Kd = 512;  nx = 16; t0 = 256; }
    else if (b < 768)  { S = Wv; D = Wqkvt + 1024 * 512; lds_ = 512;  Kd = 512;  nx = 16; t0 = 512; }
    else if (b < 1152) { S = W1; D = W1t;                lds_ = 256;  Kd = 1536; nx = 8;  t0 = 768; }
    else if (b < 1408) { S = W2; D = W2t;                lds_ = 1026; Kd = 256;  nx = 32; t0 = 1152; }
    else               { S = Wo; D = Wot;                lds_ = 512;  Kd = 512;  nx = 16; t0 = 1408; }
    const int tile = b - t0;
    const int n0 = (tile % nx) << 5, k0 = (tile / nx) << 5;
    const int tx = threadIdx.x & 31, ty8 = threadIdx.x >> 5;
    for (int yy = ty8; yy < 32; yy += 8)
      t[yy][tx] = S[(size_t)(k0 + yy) * lds_ + n0 + tx];
    __syncthreads();
    for (int yy = ty8; yy < 32; yy += 8)
      D[(size_t)(n0 + yy) * Kd + k0 + tx] = f2bf(t[tx][yy]);
  } else {
    __shared__ float Aq[32][36];
    __shared__ float Bk[32][36];
    const int tile = b - 1664;
    const int c0 = (tile >> 4) << 5, j0 = (tile & 15) << 5;
    const int tid = threadIdx.x;
    const int r = tid >> 3, ic = (tid & 7) << 2;
    const int ty = tid >> 4, tx = tid & 15;
    float a00 = 0.f, a01 = 0.f, a10 = 0.f, a11 = 0.f;
    for (int i0 = 0; i0 < 512; i0 += 32) {
      float4 a = ld4(Wq + (size_t)(c0 + r) * 512 + i0 + ic);
      float4 bb = ld4(Wk + (size_t)(j0 + r) * 512 + i0 + ic);
      Aq[r][ic] = a.x; Aq[r][ic + 1] = a.y; Aq[r][ic + 2] = a.z; Aq[r][ic + 3] = a.w;
      Bk[r][ic] = bb.x; Bk[r][ic + 1] = bb.y; Bk[r][ic + 2] = bb.z; Bk[r][ic + 3] = bb.w;
      __syncthreads();
#pragma unroll
      for (int i = 0; i < 32; ++i) {
        float x0 = Aq[ty * 2][i], x1 = Aq[ty * 2 + 1][i];
        float y0 = Bk[tx * 2][i], y1 = Bk[tx * 2 + 1][i];
        a00 += x0 * y0; a01 += x0 * y1; a10 += x1 * y0; a11 += x1 * y1;
      }
      __syncthreads();
    }
    Wqk[(size_t)(c0 + ty * 2) * 512 + j0 + tx * 2]         = a00;
    Wqk[(size_t)(c0 + ty * 2) * 512 + j0 + tx * 2 + 1]     = a01;
    Wqk[(size_t)(c0 + ty * 2 + 1) * 512 + j0 + tx * 2]     = a10;
    Wqk[(size_t)(c0 + ty * 2 + 1) * 512 + j0 + tx * 2 + 1] = a11;
  }
}

// ---------------------------------------------------------------------------
// qk = (hidden + pe0) @ Wqk   (fp32 exact, 2048x512x512)
// ---------------------------------------------------------------------------
__global__ __launch_bounds__(256) void qk_gemm(const float* __restrict__ A,
                                               const float* __restrict__ B,
                                               float* __restrict__ C,
                                               const float* __restrict__ pe) {
  __shared__ float As[16][68];
  __shared__ float Bs[16][68];
  const int tid = threadIdx.x;
  const int rm = blockIdx.y << 6, cn = blockIdx.x << 6;
  const int tx = tid & 15, ty = tid >> 4;
  const int ar = tid >> 2, ak = (tid & 3) << 2;
  const int bk = tid >> 4, bn = (tid & 15) << 2;
  const float* Ap = A + (size_t)(rm + ar) * 512;
  float acc[4][4] = {};
  for (int kt = 0; kt < 32; ++kt) {
    const int k0 = (kt << 4) + ak;
    float4 x = ld4(Ap + k0);
    float4 p4 = ld4(pe + k0);
    As[ak + 0][ar] = x.x + p4.x; As[ak + 1][ar] = x.y + p4.y;
    As[ak + 2][ar] = x.z + p4.z; As[ak + 3][ar] = x.w + p4.w;
    *(float4*)&Bs[bk][bn] = ld4(B + (size_t)((kt << 4) + bk) * 512 + cn + bn);
    __syncthreads();
#pragma unroll
    for (int kk = 0; kk < 16; ++kk) {
      float4 a = *(const float4*)&As[kk][ty << 2];
      float4 b = *(const float4*)&Bs[kk][tx << 2];
      acc[0][0] += a.x * b.x; acc[0][1] += a.x * b.y; acc[0][2] += a.x * b.z; acc[0][3] += a.x * b.w;
      acc[1][0] += a.y * b.x; acc[1][1] += a.y * b.y; acc[1][2] += a.y * b.z; acc[1][3] += a.y * b.w;
      acc[2][0] += a.z * b.x; acc[2][1] += a.z * b.y; acc[2][2] += a.z * b.z; acc[2][3] += a.z * b.w;
      acc[3][0] += a.w * b.x; acc[3][1] += a.w * b.y; acc[3][2] += a.w * b.z; acc[3][3] += a.w * b.w;
    }
    __syncthreads();
  }
  const int row0 = rm + (ty << 2), col0 = cn + (tx << 2);
#pragma unroll
  for (int i = 0; i < 4; ++i)
    *(float4*)(C + (size_t)(row0 + i) * 512 + col0) =
        make_float4(acc[i][0], acc[i][1], acc[i][2], acc[i][3]);
}

// ---------------------------------------------------------------------------
// score + top-8 + gather; writes xh = bf16(hidden+pe0), gsel = bf16(sel+pe)
// ---------------------------------------------------------------------------
__global__ __launch_bounds__(256) void score_topk_gather(
    const float* __restrict__ QK, const float* __restrict__ cached,
    const float* __restrict__ pe, const float* __restrict__ hidden,
    u16* __restrict__ xh, u16* __restrict__ gsel) {
  __shared__ float sc[32];
  __shared__ int ix[8];
  const int b0 = blockIdx.x;
  const int tid = threadIdx.x;
  const int w = tid >> 6, lane = tid & 63;
  const int off = lane << 3;
  const float* qk = QK + (size_t)b0 * 512;
  float4 q0 = ld4(qk + off);
  float4 q1 = ld4(qk + off + 4);
  for (int i = 0; i < 8; ++i) {
    const int p = (w << 3) + i;
    const float* cp = cached + ((size_t)b0 * 32 + p) * 512 + off;
    const float* pp = pe + (size_t)p * 512 + off;
    float4 c0 = ld4(cp), c1 = ld4(cp + 4);
    float4 e0 = ld4(pp), e1 = ld4(pp + 4);
    float s = (c0.x + e0.x) * q0.x + (c0.y + e0.y) * q0.y +
              (c0.z + e0.z) * q0.z + (c0.w + e0.w) * q0.w +
              (c1.x + e1.x) * q1.x + (c1.y + e1.y) * q1.y +
              (c1.z + e1.z) * q1.z + (c1.w + e1.w) * q1.w;
#pragma unroll
    for (int d = 32; d > 0; d >>= 1) s += __shfl_xor(s, d);
    if (lane == 0) sc[p] = s;
  }
  __syncthreads();
  if (tid == 0) {
    for (int r = 0; r < 8; ++r) {
      float best = -INFINITY; int bi = 0;
      for (int p = 0; p < 32; ++p) {
        float v = sc[p];
        if (v > best) { best = v; bi = p; }
      }
      ix[r] = bi;
      sc[bi] = -INFINITY;
    }
  }
  __syncthreads();
#pragma unroll
  for (int rr = 0; rr < 2; ++rr) {
    const int rsel = w + (rr << 2);
    const int p = ix[rsel];
    const float* cp = cached + ((size_t)b0 * 32 + p) * 512 + off;
    const float* pp = pe + (size_t)p * 512 + off;
    float4 c0 = ld4(cp), c1 = ld4(cp + 4);
    float4 e0 = ld4(pp), e1 = ld4(pp + 4);
    int4 o;
    o.x = pk2(c0.x + e0.x, c0.y + e0.y);
    o.y = pk2(c0.z + e0.z, c0.w + e0.w);
    o.z = pk2(c1.x + e1.x, c1.y + e1.y);
    o.w = pk2(c1.z + e1.z, c1.w + e1.w);
    *(int4*)(gsel + (size_t)(b0 * 8 + rsel) * 512 + off) = o;
  }
  if (w == 0) {
    const float* hp = hidden + (size_t)b0 * 512 + off;
    float4 a = ld4(hp), b = ld4(hp + 4);
    float4 p0 = ld4(pe + off), p1 = ld4(pe + off + 4);
    int4 o;
    o.x = pk2(a.x + p0.x, a.y + p0.y);
    o.y = pk2(a.z + p0.z, a.w + p0.w);
    o.z = pk2(b.x + p1.x, b.y + p1.y);
    o.w = pk2(b.z + p1.z, b.w + p1.w);
    *(int4*)(xh + (size_t)b0 * 512 + off) = o;
  }
}

// ---------------------------------------------------------------------------
// Fused GEMM #1 (BK=64): blocks 0-1023  kvh = gsel @ [Wk|Wv]t  (16384x1024x512)
//                        blocks 1024-1215 Yh = xh @ [Wq|Wk|Wv]t (2048x1536x512)
// ---------------------------------------------------------------------------
__global__ __launch_bounds__(256) void bgemm_fused1(
    const u16* __restrict__ gsel, const u16* __restrict__ xh,
    const u16* __restrict__ Wqkvt, u16* __restrict__ kvh,
    u16* __restrict__ Yh) {
  __shared__ u16 As[8192];
  __shared__ u16 Bs[8192];
  const int tid = threadIdx.x, lane = tid & 63, w = tid >> 6;
  const int bid = blockIdx.x;
  int rm, cn, ldc; const u16 *Ab, *Bb; u16* C;
  if (bid < 1024) {
    rm = (bid >> 3) << 7; cn = (bid & 7) << 7;
    Ab = gsel; Bb = Wqkvt + (size_t)512 * 512; C = kvh; ldc = 1024;
  } else {
    const int b2 = bid - 1024;
    rm = (b2 / 12) << 7; cn = (b2 % 12) << 7;
    Ab = xh; Bb = Wqkvt; C = Yh; ldc = 1536;
  }
  const int lrow = (w << 3) + (lane >> 3), lko = (lane & 7) << 3;
  const u16* ap = Ab + (size_t)(rm + lrow) * 512 + lko;
  const u16* bp = Bb + (size_t)(cn + lrow) * 512 + lko;
  const int aoff = ((w >> 1) << 12) + ((lane & 15) << 6) + ((lane >> 4) << 3);
  const int boff = ((w & 1) << 12) + ((lane & 15) << 6) + ((lane >> 4) << 3);
  f32x4 acc[4][4];
#pragma unroll
  for (int i = 0; i < 4; ++i)
#pragma unroll
    for (int j = 0; j < 4; ++j) acc[i][j] = (f32x4){0.f, 0.f, 0.f, 0.f};
  for (int kt = 0; kt < 8; ++kt) {
    if (kt) __syncthreads();
    stageT<4>(As, ap, 512, w);
    stageT<4>(Bs, bp, 512, w);
    ap += 64; bp += 64;
    __syncthreads();
#pragma unroll
    for (int s = 0; s < 2; ++s) {
      bf16x8 av[4], bv[4];
#pragma unroll
      for (int i = 0; i < 4; ++i) av[i] = *(const bf16x8*)(As + aoff + (i << 10) + (s << 5));
#pragma unroll
      for (int j = 0; j < 4; ++j) bv[j] = *(const bf16x8*)(Bs + boff + (j << 10) + (s << 5));
#pragma unroll
      for (int i = 0; i < 4; ++i)
#pragma unroll
        for (int j = 0; j < 4; ++j)
          acc[i][j] = __builtin_amdgcn_mfma_f32_16x16x32_bf16(bv[j], av[i], acc[i][j], 0, 0, 0);
    }
  }
  // swapped layout: row = lane&15, 4 consecutive cols per reg-quad
  const int row0 = rm + ((w >> 1) << 6) + (lane & 15);
  const int col0 = cn + ((w & 1) << 6) + ((lane >> 4) << 2);
#pragma unroll
  for (int i = 0; i < 4; ++i) {
    u16* cp = C + (size_t)(row0 + (i << 4)) * ldc + col0;
#pragma unroll
    for (int j = 0; j < 4; ++j) {
      int2 o;
      o.x = (int)pk2(acc[i][j][0], acc[i][j][1]);
      o.y = (int)pk2(acc[i][j][2], acc[i][j][3]);
      *(int2*)(cp + (j << 4)) = o;
    }
  }
}

// ---------------------------------------------------------------------------
// mlp1 + fused sg (BK=64): h = gelu([q|ksel|vsel]@W1+b1) -> hb; per-row s,g.
// BM=64, BN=256, K=1536.
// ---------------------------------------------------------------------------
__global__ __launch_bounds__(256) void mlp1_sg(
    const u16* __restrict__ Yh, const u16* __restrict__ kvh,
    const u16* __restrict__ W1t, const float* __restrict__ b1,
    const float* __restrict__ W2, const float* __restrict__ b2,
    u16* __restrict__ hb, float* __restrict__ sgv) {
  __shared__ u16 As[4096];   // [64][64]
  __shared__ u16 Bs[16384];  // [256][64]
  __shared__ float wa[256], wb[256];
  const int tid = threadIdx.x, lane = tid & 63, w = tid >> 6;
  const int rm = blockIdx.x << 6;
  wa[tid] = W2[(size_t)tid * 1026 + 1024];
  wb[tid] = W2[(size_t)tid * 1026 + 1025];
  const int lrow = (w << 3) + (lane >> 3), lko = (lane & 7) << 3;
  const u16* aq0  = Yh + (size_t)((rm + lrow) >> 3) * 1536 + lko;
  const u16* aq1  = Yh + (size_t)((rm + lrow + 32) >> 3) * 1536 + lko;
  const u16* akv0 = kvh + (size_t)(rm + lrow) * 1024 + lko;
  const u16* akv1 = kvh + (size_t)(rm + lrow + 32) * 1024 + lko;
  const u16* bp = W1t + (size_t)lrow * 1536 + lko;
  const int aoff = ((lane & 15) << 6) + ((lane >> 4) << 3);
  const int boff = (w << 12) + aoff;
  f32x4 acc[4][4];
#pragma unroll
  for (int i = 0; i < 4; ++i)
#pragma unroll
    for (int j = 0; j < 4; ++j) acc[i][j] = (f32x4){0.f, 0.f, 0.f, 0.f};
  for (int kt = 0; kt < 24; ++kt) {
    const int ko = kt << 6;
    if (kt) __syncthreads();
    if (kt < 8) {
      gld16(aq0 + ko, As + (w << 9));
      gld16(aq1 + ko, As + (w << 9) + 2048);
    } else {
      gld16(akv0 + ko - 512, As + (w << 9));
      gld16(akv1 + ko - 512, As + (w << 9) + 2048);
    }
    stageT<8>(Bs, bp, 1536, w);
    bp += 64;
    __syncthreads();
#pragma unroll
    for (int s = 0; s < 2; ++s) {
      bf16x8 av[4], bv[4];
#pragma unroll
      for (int i = 0; i < 4; ++i) av[i] = *(const bf16x8*)(As + aoff + (i << 10) + (s << 5));
#pragma unroll
      for (int j = 0; j < 4; ++j) bv[j] = *(const bf16x8*)(Bs + boff + (j << 10) + (s << 5));
#pragma unroll
      for (int i = 0; i < 4; ++i)
#pragma unroll
        for (int j = 0; j < 4; ++j)
          acc[i][j] = __builtin_amdgcn_mfma_f32_16x16x32_bf16(bv[j], av[i], acc[i][j], 0, 0, 0);
    }
  }
  const int row0 = rm + (lane & 15);
  const int col0 = (w << 6) + ((lane >> 4) << 2);
#pragma unroll
  for (int i = 0; i < 4; ++i) {
    u16* hp = hb + (size_t)(row0 + (i << 4)) * 256 + col0;
#pragma unroll
    for (int j = 0; j < 4; ++j) {
      float4 bb = ld4(b1 + col0 + (j << 4));
      int2 o;
      o.x = (int)pk2(gelu_exact(acc[i][j][0] + bb.x), gelu_exact(acc[i][j][1] + bb.y));
      o.y = (int)pk2(gelu_exact(acc[i][j][2] + bb.z), gelu_exact(acc[i][j][3] + bb.w));
      *(int2*)(hp + (j << 4)) = o;
    }
  }
  __syncthreads();
  // sg: 4 threads per row, shuffle-reduce
  const int row = tid >> 2, q = tid & 3;
  const int rr = rm + row;
  const u16* hp = hb + (size_t)rr * 256 + (q << 6);
  float pa = 0.f, pb = 0.f;
  for (int c = 0; c < 64; c += 8) {
    float h[8]; ld8bf(hp + c, h);
    const int cb = (q << 6) + c;
#pragma unroll
    for (int t = 0; t < 8; ++t) { pa += h[t] * wa[cb + t]; pb += h[t] * wb[cb + t]; }
  }
  pa += __shfl_xor(pa, 1); pa += __shfl_xor(pa, 2);
  pb += __shfl_xor(pb, 1); pb += __shfl_xor(pb, 2);
  if (q == 0) {
    const float t0 = pa + b2[1024];
    const float t1 = pb + b2[1025];
    const float s = (t0 > 0.f ? t0 + log1pf(expf(-t0)) : log1pf(expf(t0))) + 1e-5f;
    const float g = 1.f / (1.f + expf(-t1));
    sgv[2 * rr] = s; sgv[2 * rr + 1] = g;
  }
}

// ---------------------------------------------------------------------------
// delta (BK=64): kvh += g*s*(hb @ W2t + b2)   (vector bf16 RMW; 16384x1024x256)
// ---------------------------------------------------------------------------
__global__ __launch_bounds__(256) void bgemm_delta(
    const u16* __restrict__ hb, const u16* __restrict__ W2t,
    u16* __restrict__ kvh, const float* __restrict__ b2,
    const float* __restrict__ sgv) {
  __shared__ u16 As[8192];
  __shared__ u16 Bs[8192];
  const int tid = threadIdx.x, lane = tid & 63, w = tid >> 6;
  const int rm = blockIdx.y << 7, cn = blockIdx.x << 7;
  const int lrow = (w << 3) + (lane >> 3), lko = (lane & 7) << 3;
  const u16* ap = hb + (size_t)(rm + lrow) * 256 + lko;
  const u16* bp = W2t + (size_t)(cn + lrow) * 256 + lko;
  const int aoff = ((w >> 1) << 12) + ((lane & 15) << 6) + ((lane >> 4) << 3);
  const int boff = ((w & 1) << 12) + ((lane & 15) << 6) + ((lane >> 4) << 3);
  f32x4 acc[4][4];
#pragma unroll
  for (int i = 0; i < 4; ++i)
#pragma unroll
    for (int j = 0; j < 4; ++j) acc[i][j] = (f32x4){0.f, 0.f, 0.f, 0.f};
  for (int kt = 0; kt < 4; ++kt) {
    if (kt) __syncthreads();
    stageT<4>(As, ap, 256, w);
    stageT<4>(Bs, bp, 256, w);
    ap += 64; bp += 64;
    __syncthreads();
#pragma unroll
    for (int s = 0; s < 2; ++s) {
      bf16x8 av[4], bv[4];
#pragma unroll
      for (int i = 0; i < 4; ++i) av[i] = *(const bf16x8*)(As + aoff + (i << 10) + (s << 5));
#pragma unroll
      for (int j = 0; j < 4; ++j) bv[j] = *(const bf16x8*)(Bs + boff + (j << 10) + (s << 5));
#pragma unroll
      for (int i = 0; i < 4; ++i)
#pragma unroll
        for (int j = 0; j < 4; ++j)
          acc[i][j] = __builtin_amdgcn_mfma_f32_16x16x32_bf16(bv[j], av[i], acc[i][j], 0, 0, 0);
    }
  }
  const int row0 = rm + ((w >> 1) << 6) + (lane & 15);
  const int col0 = cn + ((w & 1) << 6) + ((lane >> 4) << 2);
#pragma unroll
  for (int i = 0; i < 4; ++i) {
    const int row = row0 + (i << 4);
    const float2 sg2 = *(const float2*)(sgv + (row << 1));
    const float gs = sg2.x * sg2.y;
    u16* cp = kvh + (size_t)row * 1024 + col0;
#pragma unroll
    for (int j = 0; j < 4; ++j) {
      float4 bb = ld4(b2 + col0 + (j << 4));
      int2 old = *(const int2*)(cp + (j << 4));
      const float o0 = bf2f((u16)((u32)old.x & 0xffffu)) + gs * (acc[i][j][0] + bb.x);
      const float o1 = bf2f((u16)(((u32)old.x) >> 16)) + gs * (acc[i][j][1] + bb.y);
      const float o2 = bf2f((u16)((u32)old.y & 0xffffu)) + gs * (acc[i][j][2] + bb.z);
      const float o3 = bf2f((u16)(((u32)old.y) >> 16)) + gs * (acc[i][j][3] + bb.w);
      int2 nv;
      nv.x = (int)pk2(o0, o1);
      nv.y = (int)pk2(o2, o3);
      *(int2*)(cp + (j << 4)) = nv;
    }
  }
}

// ---------------------------------------------------------------------------
// attention: one wave per token, register-only, all-bf16 inputs
// ---------------------------------------------------------------------------
__global__ __launch_bounds__(256) void attn2(const u16* __restrict__ Yh,
                                             const u16* __restrict__ kvh,
                                             u16* __restrict__ ctxh) {
  const int w = threadIdx.x >> 6, lane = threadIdx.x & 63;
  const int b0 = (blockIdx.x << 2) + w;
  const int off = lane << 3;
  const u16* yr = Yh + (size_t)b0 * 1536;
  float qv[8]; ld8bf(yr + off, qv);
  float lg[9];
#pragma unroll
  for (int k = 0; k < 9; ++k) {
    const u16* kr = (k < 8) ? (kvh + (size_t)(b0 * 8 + k) * 1024 + off)
                            : (yr + 512 + off);
    float kv[8]; ld8bf(kr, kv);
    float s = qv[0] * kv[0] + qv[1] * kv[1] + qv[2] * kv[2] + qv[3] * kv[3] +
              qv[4] * kv[4] + qv[5] * kv[5] + qv[6] * kv[6] + qv[7] * kv[7];
    s += __shfl_xor(s, 1); s += __shfl_xor(s, 2); s += __shfl_xor(s, 4);
    lg[k] = s * 0.125f;
  }
  float m = lg[0];
#pragma unroll
  for (int k = 1; k < 9; ++k) m = fmaxf(m, lg[k]);
  float sum = 0.f;
#pragma unroll
  for (int k = 0; k < 9; ++k) { lg[k] = expf(lg[k] - m); sum += lg[k]; }
  const float inv = 1.f / sum;
  float c[8] = {0.f, 0.f, 0.f, 0.f, 0.f, 0.f, 0.f, 0.f};
#pragma unroll
  for (int k = 0; k < 9; ++k) {
    const u16* vr = (k < 8) ? (kvh + (size_t)(b0 * 8 + k) * 1024 + 512 + off)
                            : (yr + 1024 + off);
    float vv[8]; ld8bf(vr, vv);
    const float wk = lg[k] * inv;
#pragma unroll
    for (int t = 0; t < 8; ++t) c[t] += wk * vv[t];
  }
  int4 o;
  o.x = pk2(c[0], c[1]); o.y = pk2(c[2], c[3]);
  o.z = pk2(c[4], c[5]); o.w = pk2(c[6], c[7]);
  *(int4*)(ctxh + (size_t)b0 * 512 + off) = o;
}

// ---------------------------------------------------------------------------
// out = ctxh @ Wot + bo   (BK=64, fp32 float4 stores; 2048x512x512)
// ---------------------------------------------------------------------------
__global__ __launch_bounds__(256) void bgemm_out(
    const u16* __restrict__ ctxh, const u16* __restrict__ Wot,
    float* __restrict__ out, const float* __restrict__ bo) {
  __shared__ u16 As[8192];
  __shared__ u16 Bs[8192];
  const int tid = threadIdx.x, lane = tid & 63, w = tid >> 6;
  const int rm = blockIdx.y << 7, cn = blockIdx.x << 7;
  const int lrow = (w << 3) + (lane >> 3), lko = (lane & 7) << 3;
  const u16* ap = ctxh + (size_t)(rm + lrow) * 512 + lko;
  const u16* bp = Wot + (size_t)(cn + lrow) * 512 + lko;
  const int aoff = ((w >> 1) << 12) + ((lane & 15) << 6) + ((lane >> 4) << 3);
  const int boff = ((w & 1) << 12) + ((lane & 15) << 6) + ((lane >> 4) << 3);
  f32x4 acc[4][4];
#pragma unroll
  for (int i = 0; i < 4; ++i)
#pragma unroll
    for (int j = 0; j < 4; ++j) acc[i][j] = (f32x4){0.f, 0.f, 0.f, 0.f};
  for (int kt = 0; kt < 8; ++kt) {
    if (kt) __syncthreads();
    stageT<4>(As, ap, 512, w);
    stageT<4>(Bs, bp, 512, w);
    ap += 64; bp += 64;
    __syncthreads();
#pragma unroll
    for (int s = 0; s < 2; ++s) {
      bf16x8 av[4], bv[4];
#pragma unroll
      for (int i = 0; i < 4; ++i) av[i] = *(const bf16x8*)(As + aoff + (i << 10) + (s << 5));
#pragma unroll
      for (int j = 0; j < 4; ++j) bv[j] = *(const bf16x8*)(Bs + boff + (j << 10) + (s << 5));
#pragma unroll
      for (int i = 0; i < 4; ++i)
#pragma unroll
        for (int j = 0; j < 4; ++j)
          acc[i][j] = __builtin_amdgcn_mfma_f32_16x16x32_bf16(bv[j], av[i], acc[i][j], 0, 0, 0);
    }
  }
  const int row0 = rm + ((w >> 1) << 6) + (lane & 15);
  const int col0 = cn + ((w & 1) << 6) + ((lane >> 4) << 2);
#pragma unroll
  for (int i = 0; i < 4; ++i) {
    float* op = out + (size_t)(row0 + (i << 4)) * 512 + col0;
#pragma unroll
    for (int j = 0; j < 4; ++j) {
      float4 bb = ld4(bo + col0 + (j << 4));
      *(float4*)(op + (j << 4)) = make_float4(acc[i][j][0] + bb.x, acc[i][j][1] + bb.y,
                                              acc[i][j][2] + bb.z, acc[i][j][3] + bb.w);
    }
  }
}

// ---------------------------------------------------------------------------
extern "C" void kernel_launch(void* const* d_in, const int* in_sizes, int n_in,
                              void* d_out, int out_size, void* d_ws, size_t ws_size,
                              hipStream_t stream) {
  const float* hidden = (const float*)d_in[0];
  const float* cached = (const float*)d_in[1];
  const float* Wq = (const float*)d_in[2];
  const float* Wk = (const float*)d_in[3];
  const float* Wv = (const float*)d_in[4];
  const float* Wo = (const float*)d_in[5];
  const float* bo = (const float*)d_in[6];
  const float* W1 = (const float*)d_in[7];
  const float* b1 = (const float*)d_in[8];
  const float* W2 = (const float*)d_in[9];
  const float* b2 = (const float*)d_in[10];
  const float* pe = (const float*)d_in[11];

  float* ws = (float*)d_ws;
  float* Wqk = ws;                          // 512*512 f32
  float* qkb = Wqk + 262144;                // 2048*512 f32
  float* sgv = qkb + 1048576;               // 16384*2 f32
  u16* Wqkvt = (u16*)(sgv + 32768);         // [1536][512]
  u16* W1t   = Wqkvt + 786432;              // [256][1536]
  u16* W2t   = W1t + 393216;                // [1024][256]
  u16* Wot   = W2t + 262144;                // [512][512]
  u16* xh    = Wot + 262144;                // [2048][512]
  u16* gsel  = xh + 1048576;                // [16384][512]
  u16* Yh    = gsel + 8388608;              // [2048][1536]  [q|k_now|v_now]
  u16* kvh   = Yh + 3145728;                // [16384][1024] [k_sel|v_sel]
  u16* hb    = kvh + 16777216;              // [16384][256]
  u16* ctxh  = hb + 4194304;                // [2048][512]
  float* out = (float*)d_out;
  (void)in_sizes; (void)n_in; (void)out_size; (void)ws_size;

  prep_all<<<dim3(1920), 256, 0, stream>>>(Wq, Wk, Wv, W1, W2, Wo,
                                           Wqkvt, W1t, W2t, Wot, Wqk);
  qk_gemm<<<dim3(8, 32), 256, 0, stream>>>(hidden, Wqk, qkb, pe);
  score_topk_gather<<<dim3(2048), 256, 0, stream>>>(qkb, cached, pe, hidden, xh, gsel);
  bgemm_fused1<<<dim3(1216), 256, 0, stream>>>(gsel, xh, Wqkvt, kvh, Yh);
  mlp1_sg<<<dim3(256), 256, 0, stream>>>(Yh, kvh, W1t, b1, W2, b2, hb, sgv);
  bgemm_delta<<<dim3(8, 128), 256, 0, stream>>>(hb, W2t, kvh, b2, sgv);
  attn2<<<dim3(512), 256, 0, stream>>>(Yh, kvh, ctxh);
  bgemm_out<<<dim3(4, 16), 256, 0, stream>>>(ctxh, Wot, out, bo);
}

// Round 8
// 441.417 us; speedup vs baseline: 1.0260x; 1.0260x over previous
//
#include <hip/hip_runtime.h>
#include <math.h>

// B0=2048 tokens, C=512, P=32 past, R=8 selected, H=8 heads, DH=64, HID=256
// fp32 exact path for top-k scores (Wqk trick); bf16 MFMA (BK=64, T2
// XOR-swizzled LDS: linear gld16 dest + pre-swizzled global source +
// swizzled ds_read) downstream.

typedef __attribute__((ext_vector_type(8))) __bf16 bf16x8;
typedef __attribute__((ext_vector_type(4))) float f32x4;
typedef unsigned short u16;
typedef unsigned int u32;

static __device__ __forceinline__ float4 ld4(const float* p) { return *(const float4*)p; }
static __device__ __forceinline__ float gelu_exact(float x) {
  return 0.5f * x * (1.0f + erff(x * 0.70710678118654752f));
}
static __device__ __forceinline__ u16 f2bf(float f) {  // RNE
  u32 u = __float_as_uint(f);
  u = (u + 0x7fffu + ((u >> 16) & 1u)) >> 16;
  return (u16)u;
}
static __device__ __forceinline__ float bf2f(u16 h) {
  return __uint_as_float(((u32)h) << 16);
}
static __device__ __forceinline__ u32 pk2(float a, float b) {
  return (u32)f2bf(a) | ((u32)f2bf(b) << 16);
}
static __device__ __forceinline__ void ld8bf(const u16* p, float* o) {
  int4 v = *(const int4*)p;
  o[0] = bf2f((u16)((u32)v.x & 0xffffu)); o[1] = bf2f((u16)(((u32)v.x) >> 16));
  o[2] = bf2f((u16)((u32)v.y & 0xffffu)); o[3] = bf2f((u16)(((u32)v.y) >> 16));
  o[4] = bf2f((u16)((u32)v.z & 0xffffu)); o[5] = bf2f((u16)(((u32)v.z) >> 16));
  o[6] = bf2f((u16)((u32)v.w & 0xffffu)); o[7] = bf2f((u16)(((u32)v.w) >> 16));
}
static __device__ __forceinline__ void gld16(const void* g, void* l) {
  __builtin_amdgcn_global_load_lds((const __attribute__((address_space(1))) void*)g,
                                   (__attribute__((address_space(3))) void*)l, 16, 0, 0);
}
// stage NI*32 rows x 64 k (u16) into lds (linear dest); source pointer must
// already include the swizzled k-quad: sp = base + (row)*ldk + skq8 where
// row = (w<<3)+(lane>>3), skq8 = (((lane&7) ^ ((lane>>3)&7)) << 3).
// LDS then holds LDS[row][q] = global[row][q ^ (row&7)] per 64-u16 row.
template <int NI>
static __device__ __forceinline__ void stageT(u16* __restrict__ lds,
                                              const u16* __restrict__ sp,
                                              int ldk, int w) {
#pragma unroll
  for (int i = 0; i < NI; ++i)
    gld16(sp + (size_t)(i << 5) * ldk, lds + (w << 9) + (i << 11));
}

// ---------------------------------------------------------------------------
// prep_all: blocks 0-1663 bf16 weight transposes; blocks 1664-1919 fp32 Wqk.
// ---------------------------------------------------------------------------
__global__ __launch_bounds__(256) void prep_all(
    const float* __restrict__ Wq, const float* __restrict__ Wk,
    const float* __restrict__ Wv, const float* __restrict__ W1,
    const float* __restrict__ W2, const float* __restrict__ Wo,
    u16* __restrict__ Wqkvt, u16* __restrict__ W1t,
    u16* __restrict__ W2t, u16* __restrict__ Wot,
    float* __restrict__ Wqk) {
  const int b = blockIdx.x;
  if (b < 1664) {
    __shared__ float t[32][33];
    const float* S; u16* D; int lds_, Kd, nx, t0;
    if (b < 256)       { S = Wq; D = Wqkvt;              lds_ = 512;  Kd = 512;  nx = 16; t0 = 0; }
    else if (b < 512)  { S = Wk; D = Wqkvt + 512 * 512;  lds_ = 512;  Kd = 512;  nx = 16; t0 = 256; }
    else if (b < 768)  { S = Wv; D = Wqkvt + 1024 * 512; lds_ = 512;  Kd = 512;  nx = 16; t0 = 512; }
    else if (b < 1152) { S = W1; D = W1t;                lds_ = 256;  Kd = 1536; nx = 8;  t0 = 768; }
    else if (b < 1408) { S = W2; D = W2t;                lds_ = 1026; Kd = 256;  nx = 32; t0 = 1152; }
    else               { S = Wo; D = Wot;                lds_ = 512;  Kd = 512;  nx = 16; t0 = 1408; }
    const int tile = b - t0;
    const int n0 = (tile % nx) << 5, k0 = (tile / nx) << 5;
    const int tx = threadIdx.x & 31, ty8 = threadIdx.x >> 5;
    for (int yy = ty8; yy < 32; yy += 8)
      t[yy][tx] = S[(size_t)(k0 + yy) * lds_ + n0 + tx];
    __syncthreads();
    for (int yy = ty8; yy < 32; yy += 8)
      D[(size_t)(n0 + yy) * Kd + k0 + tx] = f2bf(t[tx][yy]);
  } else {
    __shared__ float Aq[32][36];
    __shared__ float Bk[32][36];
    const int tile = b - 1664;
    const int c0 = (tile >> 4) << 5, j0 = (tile & 15) << 5;
    const int tid = threadIdx.x;
    const int r = tid >> 3, ic = (tid & 7) << 2;
    const int ty = tid >> 4, tx = tid & 15;
    float a00 = 0.f, a01 = 0.f, a10 = 0.f, a11 = 0.f;
    for (int i0 = 0; i0 < 512; i0 += 32) {
      float4 a = ld4(Wq + (size_t)(c0 + r) * 512 + i0 + ic);
      float4 bb = ld4(Wk + (size_t)(j0 + r) * 512 + i0 + ic);
      Aq[r][ic] = a.x; Aq[r][ic + 1] = a.y; Aq[r][ic + 2] = a.z; Aq[r][ic + 3] = a.w;
      Bk[r][ic] = bb.x; Bk[r][ic + 1] = bb.y; Bk[r][ic + 2] = bb.z; Bk[r][ic + 3] = bb.w;
      __syncthreads();
#pragma unroll
      for (int i = 0; i < 32; ++i) {
        float x0 = Aq[ty * 2][i], x1 = Aq[ty * 2 + 1][i];
        float y0 = Bk[tx * 2][i], y1 = Bk[tx * 2 + 1][i];
        a00 += x0 * y0; a01 += x0 * y1; a10 += x1 * y0; a11 += x1 * y1;
      }
      __syncthreads();
    }
    Wqk[(size_t)(c0 + ty * 2) * 512 + j0 + tx * 2]         = a00;
    Wqk[(size_t)(c0 + ty * 2) * 512 + j0 + tx * 2 + 1]     = a01;
    Wqk[(size_t)(c0 + ty * 2 + 1) * 512 + j0 + tx * 2]     = a10;
    Wqk[(size_t)(c0 + ty * 2 + 1) * 512 + j0 + tx * 2 + 1] = a11;
  }
}

// ---------------------------------------------------------------------------
// qk = (hidden + pe0) @ Wqk   (fp32 exact, 2048x512x512)
// ---------------------------------------------------------------------------
__global__ __launch_bounds__(256) void qk_gemm(const float* __restrict__ A,
                                               const float* __restrict__ B,
                                               float* __restrict__ C,
                                               const float* __restrict__ pe) {
  __shared__ float As[16][68];
  __shared__ float Bs[16][68];
  const int tid = threadIdx.x;
  const int rm = blockIdx.y << 6, cn = blockIdx.x << 6;
  const int tx = tid & 15, ty = tid >> 4;
  const int ar = tid >> 2, ak = (tid & 3) << 2;
  const int bk = tid >> 4, bn = (tid & 15) << 2;
  const float* Ap = A + (size_t)(rm + ar) * 512;
  float acc[4][4] = {};
  for (int kt = 0; kt < 32; ++kt) {
    const int k0 = (kt << 4) + ak;
    float4 x = ld4(Ap + k0);
    float4 p4 = ld4(pe + k0);
    As[ak + 0][ar] = x.x + p4.x; As[ak + 1][ar] = x.y + p4.y;
    As[ak + 2][ar] = x.z + p4.z; As[ak + 3][ar] = x.w + p4.w;
    *(float4*)&Bs[bk][bn] = ld4(B + (size_t)((kt << 4) + bk) * 512 + cn + bn);
    __syncthreads();
#pragma unroll
    for (int kk = 0; kk < 16; ++kk) {
      float4 a = *(const float4*)&As[kk][ty << 2];
      float4 b = *(const float4*)&Bs[kk][tx << 2];
      acc[0][0] += a.x * b.x; acc[0][1] += a.x * b.y; acc[0][2] += a.x * b.z; acc[0][3] += a.x * b.w;
      acc[1][0] += a.y * b.x; acc[1][1] += a.y * b.y; acc[1][2] += a.y * b.z; acc[1][3] += a.y * b.w;
      acc[2][0] += a.z * b.x; acc[2][1] += a.z * b.y; acc[2][2] += a.z * b.z; acc[2][3] += a.z * b.w;
      acc[3][0] += a.w * b.x; acc[3][1] += a.w * b.y; acc[3][2] += a.w * b.z; acc[3][3] += a.w * b.w;
    }
    __syncthreads();
  }
  const int row0 = rm + (ty << 2), col0 = cn + (tx << 2);
#pragma unroll
  for (int i = 0; i < 4; ++i)
    *(float4*)(C + (size_t)(row0 + i) * 512 + col0) =
        make_float4(acc[i][0], acc[i][1], acc[i][2], acc[i][3]);
}

// ---------------------------------------------------------------------------
// score + top-8 + gather; writes xh = bf16(hidden+pe0), gsel = bf16(sel+pe)
// ---------------------------------------------------------------------------
__global__ __launch_bounds__(256) void score_topk_gather(
    const float* __restrict__ QK, const float* __restrict__ cached,
    const float* __restrict__ pe, const float* __restrict__ hidden,
    u16* __restrict__ xh, u16* __restrict__ gsel) {
  __shared__ float sc[32];
  __shared__ int ix[8];
  const int b0 = blockIdx.x;
  const int tid = threadIdx.x;
  const int w = tid >> 6, lane = tid & 63;
  const int off = lane << 3;
  const float* qk = QK + (size_t)b0 * 512;
  float4 q0 = ld4(qk + off);
  float4 q1 = ld4(qk + off + 4);
  for (int i = 0; i < 8; ++i) {
    const int p = (w << 3) + i;
    const float* cp = cached + ((size_t)b0 * 32 + p) * 512 + off;
    const float* pp = pe + (size_t)p * 512 + off;
    float4 c0 = ld4(cp), c1 = ld4(cp + 4);
    float4 e0 = ld4(pp), e1 = ld4(pp + 4);
    float s = (c0.x + e0.x) * q0.x + (c0.y + e0.y) * q0.y +
              (c0.z + e0.z) * q0.z + (c0.w + e0.w) * q0.w +
              (c1.x + e1.x) * q1.x + (c1.y + e1.y) * q1.y +
              (c1.z + e1.z) * q1.z + (c1.w + e1.w) * q1.w;
#pragma unroll
    for (int d = 32; d > 0; d >>= 1) s += __shfl_xor(s, d);
    if (lane == 0) sc[p] = s;
  }
  __syncthreads();
  if (tid == 0) {
    for (int r = 0; r < 8; ++r) {
      float best = -INFINITY; int bi = 0;
      for (int p = 0; p < 32; ++p) {
        float v = sc[p];
        if (v > best) { best = v; bi = p; }
      }
      ix[r] = bi;
      sc[bi] = -INFINITY;
    }
  }
  __syncthreads();
#pragma unroll
  for (int rr = 0; rr < 2; ++rr) {
    const int rsel = w + (rr << 2);
    const int p = ix[rsel];
    const float* cp = cached + ((size_t)b0 * 32 + p) * 512 + off;
    const float* pp = pe + (size_t)p * 512 + off;
    float4 c0 = ld4(cp), c1 = ld4(cp + 4);
    float4 e0 = ld4(pp), e1 = ld4(pp + 4);
    int4 o;
    o.x = pk2(c0.x + e0.x, c0.y + e0.y);
    o.y = pk2(c0.z + e0.z, c0.w + e0.w);
    o.z = pk2(c1.x + e1.x, c1.y + e1.y);
    o.w = pk2(c1.z + e1.z, c1.w + e1.w);
    *(int4*)(gsel + (size_t)(b0 * 8 + rsel) * 512 + off) = o;
  }
  if (w == 0) {
    const float* hp = hidden + (size_t)b0 * 512 + off;
    float4 a = ld4(hp), b = ld4(hp + 4);
    float4 p0 = ld4(pe + off), p1 = ld4(pe + off + 4);
    int4 o;
    o.x = pk2(a.x + p0.x, a.y + p0.y);
    o.y = pk2(a.z + p0.z, a.w + p0.w);
    o.z = pk2(b.x + p1.x, b.y + p1.y);
    o.w = pk2(b.z + p1.z, b.w + p1.w);
    *(int4*)(xh + (size_t)b0 * 512 + off) = o;
  }
}

// ---------------------------------------------------------------------------
// Fused GEMM #1 (BK=64, swizzled): blocks 0-1023 kvh = gsel @ [Wk|Wv]t
//                                  blocks 1024-1215 Yh = xh @ [Wq|Wk|Wv]t
// ---------------------------------------------------------------------------
__global__ __launch_bounds__(256) void bgemm_fused1(
    const u16* __restrict__ gsel, const u16* __restrict__ xh,
    const u16* __restrict__ Wqkvt, u16* __restrict__ kvh,
    u16* __restrict__ Yh) {
  __shared__ u16 As[8192];
  __shared__ u16 Bs[8192];
  const int tid = threadIdx.x, lane = tid & 63, w = tid >> 6;
  const int bid = blockIdx.x;
  int rm, cn, ldc; const u16 *Ab, *Bb; u16* C;
  if (bid < 1024) {
    rm = (bid >> 3) << 7; cn = (bid & 7) << 7;
    Ab = gsel; Bb = Wqkvt + (size_t)512 * 512; C = kvh; ldc = 1024;
  } else {
    const int b2 = bid - 1024;
    rm = (b2 / 12) << 7; cn = (b2 % 12) << 7;
    Ab = xh; Bb = Wqkvt; C = Yh; ldc = 1536;
  }
  const int lrow = (w << 3) + (lane >> 3);
  const int skq8 = (((lane & 7) ^ ((lane >> 3) & 7)) << 3);  // swizzled src quad
  const u16* ap = Ab + (size_t)(rm + lrow) * 512 + skq8;
  const u16* bp = Bb + (size_t)(cn + lrow) * 512 + skq8;
  const int abase = ((w >> 1) << 12) + ((lane & 15) << 6);
  const int bbase = ((w & 1) << 12) + ((lane & 15) << 6);
  f32x4 acc[4][4];
#pragma unroll
  for (int i = 0; i < 4; ++i)
#pragma unroll
    for (int j = 0; j < 4; ++j) acc[i][j] = (f32x4){0.f, 0.f, 0.f, 0.f};
  for (int kt = 0; kt < 8; ++kt) {
    if (kt) __syncthreads();
    stageT<4>(As, ap, 512, w);
    stageT<4>(Bs, bp, 512, w);
    ap += 64; bp += 64;
    __syncthreads();
#pragma unroll
    for (int s = 0; s < 2; ++s) {
      const int sq = ((((lane >> 4) | (s << 2)) ^ (lane & 7)) << 3);
      bf16x8 av[4], bv[4];
#pragma unroll
      for (int i = 0; i < 4; ++i) av[i] = *(const bf16x8*)(As + abase + (i << 10) + sq);
#pragma unroll
      for (int j = 0; j < 4; ++j) bv[j] = *(const bf16x8*)(Bs + bbase + (j << 10) + sq);
#pragma unroll
      for (int i = 0; i < 4; ++i)
#pragma unroll
        for (int j = 0; j < 4; ++j)
          acc[i][j] = __builtin_amdgcn_mfma_f32_16x16x32_bf16(bv[j], av[i], acc[i][j], 0, 0, 0);
    }
  }
  const int row0 = rm + ((w >> 1) << 6) + (lane & 15);
  const int col0 = cn + ((w & 1) << 6) + ((lane >> 4) << 2);
#pragma unroll
  for (int i = 0; i < 4; ++i) {
    u16* cp = C + (size_t)(row0 + (i << 4)) * ldc + col0;
#pragma unroll
    for (int j = 0; j < 4; ++j) {
      int2 o;
      o.x = (int)pk2(acc[i][j][0], acc[i][j][1]);
      o.y = (int)pk2(acc[i][j][2], acc[i][j][3]);
      *(int2*)(cp + (j << 4)) = o;
    }
  }
}

// ---------------------------------------------------------------------------
// mlp1 (BM=64, BN=128, K=1536, swizzled): h = gelu([q|ksel|vsel]@W1+b1) -> hb
// grid (2, 256) = 512 blocks (2 blocks/CU).
// ---------------------------------------------------------------------------
__global__ __launch_bounds__(256) void mlp1(
    const u16* __restrict__ Yh, const u16* __restrict__ kvh,
    const u16* __restrict__ W1t, const float* __restrict__ b1,
    u16* __restrict__ hb) {
  __shared__ u16 As[4096];   // [64][64]
  __shared__ u16 Bs[8192];   // [128][64]
  const int tid = threadIdx.x, lane = tid & 63, w = tid >> 6;
  const int rm = blockIdx.y << 6, cn = blockIdx.x << 7;
  const int lrow = (w << 3) + (lane >> 3);
  const int skq8 = (((lane & 7) ^ ((lane >> 3) & 7)) << 3);
  const u16* aq0  = Yh + (size_t)((rm + lrow) >> 3) * 1536 + skq8;
  const u16* aq1  = Yh + (size_t)((rm + lrow + 32) >> 3) * 1536 + skq8;
  const u16* akv0 = kvh + (size_t)(rm + lrow) * 1024 + skq8;
  const u16* akv1 = kvh + (size_t)(rm + lrow + 32) * 1024 + skq8;
  const u16* bp = W1t + (size_t)(cn + lrow) * 1536 + skq8;
  const int abase = ((lane & 15) << 6);
  const int bbase = (((w << 5) + (lane & 15)) << 6);
  f32x4 acc[4][2];
#pragma unroll
  for (int i = 0; i < 4; ++i)
#pragma unroll
    for (int j = 0; j < 2; ++j) acc[i][j] = (f32x4){0.f, 0.f, 0.f, 0.f};
  for (int kt = 0; kt < 24; ++kt) {
    const int ko = kt << 6;
    if (kt) __syncthreads();
    if (kt < 8) {
      gld16(aq0 + ko, As + (w << 9));
      gld16(aq1 + ko, As + 2048 + (w << 9));
    } else {
      gld16(akv0 + ko - 512, As + (w << 9));
      gld16(akv1 + ko - 512, As + 2048 + (w << 9));
    }
    stageT<4>(Bs, bp, 1536, w);
    bp += 64;
    __syncthreads();
#pragma unroll
    for (int s = 0; s < 2; ++s) {
      const int sq = ((((lane >> 4) | (s << 2)) ^ (lane & 7)) << 3);
      bf16x8 av[4], bv[2];
#pragma unroll
      for (int i = 0; i < 4; ++i) av[i] = *(const bf16x8*)(As + abase + (i << 10) + sq);
#pragma unroll
      for (int j = 0; j < 2; ++j) bv[j] = *(const bf16x8*)(Bs + bbase + (j << 10) + sq);
#pragma unroll
      for (int i = 0; i < 4; ++i)
#pragma unroll
        for (int j = 0; j < 2; ++j)
          acc[i][j] = __builtin_amdgcn_mfma_f32_16x16x32_bf16(bv[j], av[i], acc[i][j], 0, 0, 0);
    }
  }
  const int row0 = rm + (lane & 15);
  const int col0 = cn + (w << 5) + ((lane >> 4) << 2);
#pragma unroll
  for (int i = 0; i < 4; ++i) {
    u16* hp = hb + (size_t)(row0 + (i << 4)) * 256 + col0;
#pragma unroll
    for (int j = 0; j < 2; ++j) {
      float4 bb = ld4(b1 + col0 + (j << 4));
      int2 o;
      o.x = (int)pk2(gelu_exact(acc[i][j][0] + bb.x), gelu_exact(acc[i][j][1] + bb.y));
      o.y = (int)pk2(gelu_exact(acc[i][j][2] + bb.z), gelu_exact(acc[i][j][3] + bb.w));
      *(int2*)(hp + (j << 4)) = o;
    }
  }
}

// ---------------------------------------------------------------------------
// delta + fused sg (BK=64, swizzled): per-block sg from hb rows, then
// kvh += g*s*(hb @ W2t + b2).  grid (8, 128).
// ---------------------------------------------------------------------------
__global__ __launch_bounds__(256) void bgemm_delta_sg(
    const u16* __restrict__ hb, const u16* __restrict__ W2t,
    u16* __restrict__ kvh, const float* __restrict__ W2,
    const float* __restrict__ b2) {
  __shared__ u16 As[8192];
  __shared__ u16 Bs[8192];
  __shared__ float wa_s[256], wb_s[256];
  __shared__ float2 sg_s[128];
  const int tid = threadIdx.x, lane = tid & 63, w = tid >> 6;
  const int rm = blockIdx.y << 7, cn = blockIdx.x << 7;
  wa_s[tid] = W2[(size_t)tid * 1026 + 1024];
  wb_s[tid] = W2[(size_t)tid * 1026 + 1025];
  __syncthreads();
  // sg: thread t -> row t>>1, output t&1
  {
    const int row = tid >> 1, sel = tid & 1;
    const float* wsel = sel ? wb_s : wa_s;
    const u16* hp = hb + (size_t)(rm + row) * 256;
    float d = 0.f;
    for (int c = 0; c < 256; c += 8) {
      float h[8]; ld8bf(hp + c, h);
#pragma unroll
      for (int t = 0; t < 8; ++t) d += h[t] * wsel[c + t];
    }
    if (sel == 0) {
      const float t0 = d + b2[1024];
      sg_s[row].x = (t0 > 0.f ? t0 + log1pf(expf(-t0)) : log1pf(expf(t0))) + 1e-5f;
    } else {
      const float t1 = d + b2[1025];
      sg_s[row].y = 1.f / (1.f + expf(-t1));
    }
  }
  const int lrow = (w << 3) + (lane >> 3);
  const int skq8 = (((lane & 7) ^ ((lane >> 3) & 7)) << 3);
  const u16* ap = hb + (size_t)(rm + lrow) * 256 + skq8;
  const u16* bp = W2t + (size_t)(cn + lrow) * 256 + skq8;
  const int abase = ((w >> 1) << 12) + ((lane & 15) << 6);
  const int bbase = ((w & 1) << 12) + ((lane & 15) << 6);
  f32x4 acc[4][4];
#pragma unroll
  for (int i = 0; i < 4; ++i)
#pragma unroll
    for (int j = 0; j < 4; ++j) acc[i][j] = (f32x4){0.f, 0.f, 0.f, 0.f};
  __syncthreads();  // sg_s ready; LDS free for staging
  for (int kt = 0; kt < 4; ++kt) {
    if (kt) __syncthreads();
    stageT<4>(As, ap, 256, w);
    stageT<4>(Bs, bp, 256, w);
    ap += 64; bp += 64;
    __syncthreads();
#pragma unroll
    for (int s = 0; s < 2; ++s) {
      const int sq = ((((lane >> 4) | (s << 2)) ^ (lane & 7)) << 3);
      bf16x8 av[4], bv[4];
#pragma unroll
      for (int i = 0; i < 4; ++i) av[i] = *(const bf16x8*)(As + abase + (i << 10) + sq);
#pragma unroll
      for (int j = 0; j < 4; ++j) bv[j] = *(const bf16x8*)(Bs + bbase + (j << 10) + sq);
#pragma unroll
      for (int i = 0; i < 4; ++i)
#pragma unroll
        for (int j = 0; j < 4; ++j)
          acc[i][j] = __builtin_amdgcn_mfma_f32_16x16x32_bf16(bv[j], av[i], acc[i][j], 0, 0, 0);
    }
  }
  const int rloc0 = ((w >> 1) << 6) + (lane & 15);
  const int col0 = cn + ((w & 1) << 6) + ((lane >> 4) << 2);
#pragma unroll
  for (int i = 0; i < 4; ++i) {
    const int rloc = rloc0 + (i << 4);
    const float2 sg2 = sg_s[rloc];
    const float gs = sg2.x * sg2.y;
    u16* cp = kvh + (size_t)(rm + rloc) * 1024 + col0;
#pragma unroll
    for (int j = 0; j < 4; ++j) {
      float4 bb = ld4(b2 + col0 + (j << 4));
      int2 old = *(const int2*)(cp + (j << 4));
      const float o0 = bf2f((u16)((u32)old.x & 0xffffu)) + gs * (acc[i][j][0] + bb.x);
      const float o1 = bf2f((u16)(((u32)old.x) >> 16)) + gs * (acc[i][j][1] + bb.y);
      const float o2 = bf2f((u16)((u32)old.y & 0xffffu)) + gs * (acc[i][j][2] + bb.z);
      const float o3 = bf2f((u16)(((u32)old.y) >> 16)) + gs * (acc[i][j][3] + bb.w);
      int2 nv;
      nv.x = (int)pk2(o0, o1);
      nv.y = (int)pk2(o2, o3);
      *(int2*)(cp + (j << 4)) = nv;
    }
  }
}

// ---------------------------------------------------------------------------
// attention: one wave per token, register-only, all-bf16 inputs
// ---------------------------------------------------------------------------
__global__ __launch_bounds__(256) void attn2(const u16* __restrict__ Yh,
                                             const u16* __restrict__ kvh,
                                             u16* __restrict__ ctxh) {
  const int w = threadIdx.x >> 6, lane = threadIdx.x & 63;
  const int b0 = (blockIdx.x << 2) + w;
  const int off = lane << 3;
  const u16* yr = Yh + (size_t)b0 * 1536;
  float qv[8]; ld8bf(yr + off, qv);
  float lg[9];
#pragma unroll
  for (int k = 0; k < 9; ++k) {
    const u16* kr = (k < 8) ? (kvh + (size_t)(b0 * 8 + k) * 1024 + off)
                            : (yr + 512 + off);
    float kv[8]; ld8bf(kr, kv);
    float s = qv[0] * kv[0] + qv[1] * kv[1] + qv[2] * kv[2] + qv[3] * kv[3] +
              qv[4] * kv[4] + qv[5] * kv[5] + qv[6] * kv[6] + qv[7] * kv[7];
    s += __shfl_xor(s, 1); s += __shfl_xor(s, 2); s += __shfl_xor(s, 4);
    lg[k] = s * 0.125f;
  }
  float m = lg[0];
#pragma unroll
  for (int k = 1; k < 9; ++k) m = fmaxf(m, lg[k]);
  float sum = 0.f;
#pragma unroll
  for (int k = 0; k < 9; ++k) { lg[k] = expf(lg[k] - m); sum += lg[k]; }
  const float inv = 1.f / sum;
  float c[8] = {0.f, 0.f, 0.f, 0.f, 0.f, 0.f, 0.f, 0.f};
#pragma unroll
  for (int k = 0; k < 9; ++k) {
    const u16* vr = (k < 8) ? (kvh + (size_t)(b0 * 8 + k) * 1024 + 512 + off)
                            : (yr + 1024 + off);
    float vv[8]; ld8bf(vr, vv);
    const float wk = lg[k] * inv;
#pragma unroll
    for (int t = 0; t < 8; ++t) c[t] += wk * vv[t];
  }
  int4 o;
  o.x = pk2(c[0], c[1]); o.y = pk2(c[2], c[3]);
  o.z = pk2(c[4], c[5]); o.w = pk2(c[6], c[7]);
  *(int4*)(ctxh + (size_t)b0 * 512 + off) = o;
}

// ---------------------------------------------------------------------------
// out = ctxh @ Wot + bo   (BK=64, swizzled, fp32 stores; 2048x512x512)
// ---------------------------------------------------------------------------
__global__ __launch_bounds__(256) void bgemm_out(
    const u16* __restrict__ ctxh, const u16* __restrict__ Wot,
    float* __restrict__ out, const float* __restrict__ bo) {
  __shared__ u16 As[8192];
  __shared__ u16 Bs[8192];
  const int tid = threadIdx.x, lane = tid & 63, w = tid >> 6;
  const int rm = blockIdx.y << 7, cn = blockIdx.x << 7;
  const int lrow = (w << 3) + (lane >> 3);
  const int skq8 = (((lane & 7) ^ ((lane >> 3) & 7)) << 3);
  const u16* ap = ctxh + (size_t)(rm + lrow) * 512 + skq8;
  const u16* bp = Wot + (size_t)(cn + lrow) * 512 + skq8;
  const int abase = ((w >> 1) << 12) + ((lane & 15) << 6);
  const int bbase = ((w & 1) << 12) + ((lane & 15) << 6);
  f32x4 acc[4][4];
#pragma unroll
  for (int i = 0; i < 4; ++i)
#pragma unroll
    for (int j = 0; j < 4; ++j) acc[i][j] = (f32x4){0.f, 0.f, 0.f, 0.f};
  for (int kt = 0; kt < 8; ++kt) {
    if (kt) __syncthreads();
    stageT<4>(As, ap, 512, w);
    stageT<4>(Bs, bp, 512, w);
    ap += 64; bp += 64;
    __syncthreads();
#pragma unroll
    for (int s = 0; s < 2; ++s) {
      const int sq = ((((lane >> 4) | (s << 2)) ^ (lane & 7)) << 3);
      bf16x8 av[4], bv[4];
#pragma unroll
      for (int i = 0; i < 4; ++i) av[i] = *(const bf16x8*)(As + abase + (i << 10) + sq);
#pragma unroll
      for (int j = 0; j < 4; ++j) bv[j] = *(const bf16x8*)(Bs + bbase + (j << 10) + sq);
#pragma unroll
      for (int i = 0; i < 4; ++i)
#pragma unroll
        for (int j = 0; j < 4; ++j)
          acc[i][j] = __builtin_amdgcn_mfma_f32_16x16x32_bf16(bv[j], av[i], acc[i][j], 0, 0, 0);
    }
  }
  const int row0 = rm + ((w >> 1) << 6) + (lane & 15);
  const int col0 = cn + ((w & 1) << 6) + ((lane >> 4) << 2);
#pragma unroll
  for (int i = 0; i < 4; ++i) {
    float* op = out + (size_t)(row0 + (i << 4)) * 512 + col0;
#pragma unroll
    for (int j = 0; j < 4; ++j) {
      float4 bb = ld4(bo + col0 + (j << 4));
      *(float4*)(op + (j << 4)) = make_float4(acc[i][j][0] + bb.x, acc[i][j][1] + bb.y,
                                              acc[i][j][2] + bb.z, acc[i][j][3] + bb.w);
    }
  }
}

// ---------------------------------------------------------------------------
extern "C" void kernel_launch(void* const* d_in, const int* in_sizes, int n_in,
                              void* d_out, int out_size, void* d_ws, size_t ws_size,
                              hipStream_t stream) {
  const float* hidden = (const float*)d_in[0];
  const float* cached = (const float*)d_in[1];
  const float* Wq = (const float*)d_in[2];
  const float* Wk = (const float*)d_in[3];
  const float* Wv = (const float*)d_in[4];
  const float* Wo = (const float*)d_in[5];
  const float* bo = (const float*)d_in[6];
  const float* W1 = (const float*)d_in[7];
  const float* b1 = (const float*)d_in[8];
  const float* W2 = (const float*)d_in[9];
  const float* b2 = (const float*)d_in[10];
  const float* pe = (const float*)d_in[11];

  float* ws = (float*)d_ws;
  float* Wqk = ws;                          // 512*512 f32
  float* qkb = Wqk + 262144;                // 2048*512 f32
  u16* Wqkvt = (u16*)(qkb + 1048576);       // [1536][512]
  u16* W1t   = Wqkvt + 786432;              // [256][1536]
  u16* W2t   = W1t + 393216;                // [1024][256]
  u16* Wot   = W2t + 262144;                // [512][512]
  u16* xh    = Wot + 262144;                // [2048][512]
  u16* gsel  = xh + 1048576;                // [16384][512]
  u16* Yh    = gsel + 8388608;              // [2048][1536]  [q|k_now|v_now]
  u16* kvh   = Yh + 3145728;                // [16384][1024] [k_sel|v_sel]
  u16* hb    = kvh + 16777216;              // [16384][256]
  u16* ctxh  = hb + 4194304;                // [2048][512]
  float* out = (float*)d_out;
  (void)in_sizes; (void)n_in; (void)out_size; (void)ws_size;

  prep_all<<<dim3(1920), 256, 0, stream>>>(Wq, Wk, Wv, W1, W2, Wo,
                                           Wqkvt, W1t, W2t, Wot, Wqk);
  qk_gemm<<<dim3(8, 32), 256, 0, stream>>>(hidden, Wqk, qkb, pe);
  score_topk_gather<<<dim3(2048), 256, 0, stream>>>(qkb, cached, pe, hidden, xh, gsel);
  bgemm_fused1<<<dim3(1216), 256, 0, stream>>>(gsel, xh, Wqkvt, kvh, Yh);
  mlp1<<<dim3(2, 256), 256, 0, stream>>>(Yh, kvh, W1t, b1, hb);
  bgemm_delta_sg<<<dim3(8, 128), 256, 0, stream>>>(hb, W2t, kvh, W2, b2);
  attn2<<<dim3(512), 256, 0, stream>>>(Yh, kvh, ctxh);
  bgemm_out<<<dim3(4, 16), 256, 0, stream>>>(ctxh, Wot, out, bo);
}